// Round 14
// baseline (124.579 us; speedup 1.0000x reference)
//
#include <hip/hip_runtime.h>
#include <hip/hip_bf16.h>
#include <math.h>

#define EMBED 128
#define VOCAB 32000
#define MEMN  50
#define BATCH 16
#define NQ    10
#define SQ    20
#define SS    40
#define BN    (BATCH*NQ)   // 160
#define NHOPS 3

#define NHOPSBLK 160       // kernel2: one query per block
#define NGEMMBLK 250       // kernel2: 4 waves x 2 items x 16 cols = 32000/250 per block
#define K2BLOCKS (NHOPSBLK + NGEMMBLK)   // 410 <= 512 resident (55KB LDS -> 2/CU)

typedef short v8s __attribute__((ext_vector_type(8)));
typedef float v4f __attribute__((ext_vector_type(4)));

#define MFMA16 __builtin_amdgcn_mfma_f32_16x16x32_bf16

__device__ __forceinline__ float posw(int j, int J, int k) {
    float jf = (float)(j + 1) / (float)J;
    return 1.0f - jf - ((float)(k + 1) / (float)EMBED) * (1.0f - 2.0f * jf);
}

__device__ __forceinline__ short f2bf(float f) {
    __hip_bfloat16 h = __float2bfloat16(f);
    return *(short*)&h;
}

// ---- Kernel 1: query embed [0,160) | story embed [160,960) | counter zero [960] ----
__global__ void k_embed(const int* __restrict__ cq, const int* __restrict__ story,
                        const float* __restrict__ Bw, const float* __restrict__ Aw,
                        const float* __restrict__ Cw, const float* __restrict__ TA,
                        const float* __restrict__ TC,
                        float* __restrict__ state, float* __restrict__ memb,
                        float* __restrict__ outb, unsigned* __restrict__ counter) {
    int blk = blockIdx.x;
    int t = threadIdx.x;   // 128
    if (blk < BN) {
        float acc = 0.f;
        #pragma unroll
        for (int s = 0; s < SQ; ++s) {
            int tok = cq[blk * SQ + s];
            acc += Bw[tok * EMBED + t] * posw(s, SQ, t);
        }
        state[blk * EMBED + t] = acc;
    } else if (blk < BN + BATCH * MEMN) {
        int br = blk - BN;
        int r = br % MEMN;
        float ma = TA[r * EMBED + t];
        float mc = TC[r * EMBED + t];
        const int* toks = story + br * SS;
        #pragma unroll 4
        for (int s = 0; s < SS; ++s) {
            int tok = toks[s];
            float w = posw(s, SS, t);
            ma += Aw[tok * EMBED + t] * w;
            mc += Cw[tok * EMBED + t] * w;
        }
        memb[br * EMBED + t] = ma;
        outb[br * EMBED + t] = mc;
    } else {
        if (t == 0) *counter = 0u;   // replay/poison-safe: zeroed before kernel2 runs
    }
}

// ---- Kernel 2: fused hops + classifier GEMM.
// Blocks 0..159: hops for query bn=blk (4 waves), emit stateF, release-count.
// Blocks 160..409: per wave, 2 items x 16 vocab cols. Prefetch+convert item-0
//   weights FIRST, acquire-spin on counter==160, then MFMA+store both items.
//   Coverage: 250 blk x 4 waves x 2 items x 16 cols = 32000 = VOCAB (R13 bug fixed).
__global__ __launch_bounds__(256) void k_fused(const float* __restrict__ memb,
                                               const float* __restrict__ outb,
                                               const float* __restrict__ Hw,
                                               const float* __restrict__ Hb,
                                               const float* __restrict__ state,
                                               const float* __restrict__ outw,
                                               __hip_bfloat16* __restrict__ stateF,
                                               unsigned* __restrict__ counter,
                                               float* __restrict__ out) {
    __shared__ float lmem[MEMN][EMBED + 1];
    __shared__ float lout[MEMN][EMBED + 1];
    __shared__ float lstate[EMBED];
    __shared__ float lpart[4][52];
    __shared__ float lprobs[52];
    __shared__ float lrespp[2][EMBED];
    __shared__ float lHp[2][EMBED];

    int blk = blockIdx.x;
    int t = threadIdx.x;    // 256
    int w = t >> 6;         // wave 0..3
    int l = t & 63;

    if (blk < NHOPSBLK) {
        // ================= HOPS: query bn = blk =================
        int bn = blk;
        int b  = bn / NQ;
        int d  = t & 127;
        int h  = t >> 7;    // half 0/1

        {
            const float4* mb4 = (const float4*)(memb + (size_t)b * MEMN * EMBED);
            const float4* ob4 = (const float4*)(outb + (size_t)b * MEMN * EMBED);
            for (int i = t; i < MEMN * EMBED / 4; i += 256) {
                int r = i >> 5, c = (i & 31) << 2;
                float4 v = mb4[i];
                lmem[r][c] = v.x; lmem[r][c+1] = v.y; lmem[r][c+2] = v.z; lmem[r][c+3] = v.w;
                float4 u = ob4[i];
                lout[r][c] = u.x; lout[r][c+1] = u.y; lout[r][c+2] = u.z; lout[r][c+3] = u.w;
            }
            if (t < EMBED) lstate[t] = state[bn * EMBED + t];
        }
        float hbd = (t < EMBED) ? Hb[t] : 0.f;
        __syncthreads();

        for (int hop = 0; hop < NHOPS; ++hop) {
            // logits split-K-4: wave w covers dims [w*32, w*32+32), lane l = row
            if (l < MEMN) {
                int d0 = w << 5;
                float a0 = 0.f, a1 = 0.f, a2 = 0.f, a3 = 0.f;
                #pragma unroll
                for (int j = 0; j < 32; j += 4) {
                    a0 += lmem[l][d0 + j]     * lstate[d0 + j];
                    a1 += lmem[l][d0 + j + 1] * lstate[d0 + j + 1];
                    a2 += lmem[l][d0 + j + 2] * lstate[d0 + j + 2];
                    a3 += lmem[l][d0 + j + 3] * lstate[d0 + j + 3];
                }
                lpart[w][l] = (a0 + a1) + (a2 + a3);
            }
            __syncthreads();
            // softmax in wave 0
            if (t < 64) {
                float lg = (t < MEMN)
                    ? (lpart[0][t] + lpart[1][t]) + (lpart[2][t] + lpart[3][t]) : -1e30f;
                float mx = lg;
                #pragma unroll
                for (int off = 32; off; off >>= 1) mx = fmaxf(mx, __shfl_xor(mx, off, 64));
                float e = (t < MEMN) ? __expf(lg - mx) : 0.f;
                float ss = e;
                #pragma unroll
                for (int off = 32; off; off >>= 1) ss += __shfl_xor(ss, off, 64);
                if (t < MEMN) lprobs[t] = e / ss;
            }
            __syncthreads();
            // response halves: half h covers rows [h*25, h*25+25)
            {
                float r0 = 0.f, r1 = 0.f;
                int k0 = h * 25;
                #pragma unroll
                for (int k = 0; k < 24; k += 2) {
                    r0 += lprobs[k0 + k]     * lout[k0 + k][d];
                    r1 += lprobs[k0 + k + 1] * lout[k0 + k + 1][d];
                }
                r0 += lprobs[k0 + 24] * lout[k0 + 24][d];
                lrespp[h][d] = r0 + r1;
            }
            __syncthreads();
            // H halves: half h covers k in [h*64, h*64+64); Hw row d contiguous
            {
                int ks = h << 6;
                const float4* hw4 = (const float4*)&Hw[(size_t)d * EMBED + ks];
                float a0 = 0.f, a1 = 0.f, a2 = 0.f, a3 = 0.f;
                #pragma unroll
                for (int j = 0; j < 16; ++j) {
                    float4 wv = hw4[j];
                    int k = ks + (j << 2);
                    a0 += (lrespp[0][k]     + lrespp[1][k])     * wv.x;
                    a1 += (lrespp[0][k + 1] + lrespp[1][k + 1]) * wv.y;
                    a2 += (lrespp[0][k + 2] + lrespp[1][k + 2]) * wv.z;
                    a3 += (lrespp[0][k + 3] + lrespp[1][k + 3]) * wv.w;
                }
                lHp[h][d] = (a0 + a1) + (a2 + a3);
            }
            __syncthreads();
            if (t < EMBED) {
                float ns = hbd + lstate[t] + lHp[0][t] + lHp[1][t];
                lstate[t] = ns;
            }
            __syncthreads();
        }
        // emit stateF (MFMA A-fragment layout); publish via release counter
        if (t < EMBED) {
            int frag = ((t >> 5) << 2) | ((t >> 3) & 3);
            stateF[((size_t)frag * BN + bn) * 8 + (t & 7)] = __float2bfloat16(lstate[t]);
        }
        __syncthreads();
        if (t == 0)
            __hip_atomic_fetch_add(counter, 1u, __ATOMIC_RELEASE, __HIP_MEMORY_SCOPE_AGENT);
    } else {
        // ================= GEMM: 2 items per wave, zero-LDS (R4-proven) ==========
        int witem = (blk - NHOPSBLK) * 4 + w;   // 0..999
        int col16 = l & 15;
        int kg = l >> 4;
        const v8s* aF = (const v8s*)stateF;

        #pragma unroll
        for (int it = 0; it < 2; ++it) {
            int v = (witem + it * 1000) * 16 + col16;   // covers 0..31999
            // prefetch + convert weights (item 0's issue before the spin)
            v8s bfrag[4];
            #pragma unroll
            for (int k4 = 0; k4 < 4; ++k4) {
                const float4* p = (const float4*)&outw[(size_t)v * EMBED + k4 * 32 + kg * 8];
                float4 w0 = p[0], w1 = p[1];
                v8s bf;
                bf[0] = f2bf(w0.x); bf[1] = f2bf(w0.y); bf[2] = f2bf(w0.z); bf[3] = f2bf(w0.w);
                bf[4] = f2bf(w1.x); bf[5] = f2bf(w1.y); bf[6] = f2bf(w1.z); bf[7] = f2bf(w1.w);
                bfrag[k4] = bf;
            }
            if (it == 0) {
                while (__hip_atomic_load(counter, __ATOMIC_ACQUIRE, __HIP_MEMORY_SCOPE_AGENT)
                       < (unsigned)NHOPSBLK)
                    __builtin_amdgcn_s_sleep(8);
            }
            v4f acc[10];
            #pragma unroll
            for (int m = 0; m < 10; ++m) acc[m] = (v4f){0.f, 0.f, 0.f, 0.f};
            #pragma unroll
            for (int k4 = 0; k4 < 4; ++k4) {
                v8s af[10];
                #pragma unroll
                for (int m = 0; m < 10; ++m)
                    af[m] = aF[(((k4 << 2) | kg) * BN) + m * 16 + col16];
                #pragma unroll
                for (int m = 0; m < 10; ++m)
                    acc[m] = MFMA16(af[m], bfrag[k4], acc[m], 0, 0, 0);
            }
            #pragma unroll
            for (int m = 0; m < 10; ++m) {
                #pragma unroll
                for (int i = 0; i < 4; ++i)
                    out[(size_t)(m * 16 + kg * 4 + i) * VOCAB + v] = acc[m][i];
            }
        }
    }
}

extern "C" void kernel_launch(void* const* d_in, const int* in_sizes, int n_in,
                              void* d_out, int out_size, void* d_ws, size_t ws_size,
                              hipStream_t stream) {
    const int*   ctx_query = (const int*)  d_in[0];
    const int*   story     = (const int*)  d_in[1];
    const float* A_w       = (const float*)d_in[2];
    const float* C_w       = (const float*)d_in[3];
    const float* B_w       = (const float*)d_in[4];
    const float* H_w       = (const float*)d_in[5];
    const float* H_b       = (const float*)d_in[6];
    const float* out_w     = (const float*)d_in[7];
    const float* TA        = (const float*)d_in[8];
    const float* TC        = (const float*)d_in[9];
    float* out = (float*)d_out;

    float* ws    = (float*)d_ws;
    float* state = ws;                                    // 160*128 f32
    float* memb  = state + BN * EMBED;                    // 800*128 f32
    float* outb  = memb + BATCH * MEMN * EMBED;           // 800*128 f32
    __hip_bfloat16* stateF = (__hip_bfloat16*)(outb + BATCH * MEMN * EMBED); // 160*128 bf16
    unsigned* counter = (unsigned*)(stateF + BN * EMBED); // 1 (own line)

    k_embed<<<BN + BATCH * MEMN + 1, 128, 0, stream>>>(
        ctx_query, story, B_w, A_w, C_w, TA, TC, state, memb, outb, counter);
    k_fused<<<K2BLOCKS, 256, 0, stream>>>(
        memb, outb, H_w, H_b, state, out_w, stateF, counter, out);
}

// Round 15
// 30.909 us; speedup vs baseline: 4.0305x; 4.0305x over previous
//
#include <hip/hip_runtime.h>
#include <hip/hip_bf16.h>
#include <math.h>

#define EMBED 128
#define VOCAB 32000
#define MEMN  50
#define BATCH 16
#define NQ    10
#define SQ    20
#define SS    40
#define BN    (BATCH*NQ)   // 160
#define NHOPS 3
#define NV    64           // vocab rows per k_out block

typedef short v8s __attribute__((ext_vector_type(8)));
typedef float v4f __attribute__((ext_vector_type(4)));

#define MFMA16 __builtin_amdgcn_mfma_f32_16x16x32_bf16

__device__ __forceinline__ float posw(int j, int J, int k) {
    float jf = (float)(j + 1) / (float)J;
    return 1.0f - jf - ((float)(k + 1) / (float)EMBED) * (1.0f - 2.0f * jf);
}

__device__ __forceinline__ short f2bf(float f) {
    __hip_bfloat16 h = __float2bfloat16(f);
    return *(short*)&h;
}

// ---- Kernel 1 (R8-form, HwT branch removed): query | story ----
__global__ void k_embed(const int* __restrict__ cq, const int* __restrict__ story,
                        const float* __restrict__ Bw, const float* __restrict__ Aw,
                        const float* __restrict__ Cw, const float* __restrict__ TA,
                        const float* __restrict__ TC,
                        float* __restrict__ state, float* __restrict__ memb,
                        float* __restrict__ outb) {
    int blk = blockIdx.x;
    int t = threadIdx.x;   // 128
    if (blk < BN) {
        float acc = 0.f;
        #pragma unroll
        for (int s = 0; s < SQ; ++s) {
            int tok = cq[blk * SQ + s];
            acc += Bw[tok * EMBED + t] * posw(s, SQ, t);
        }
        state[blk * EMBED + t] = acc;
    } else {
        int br = blk - BN;
        int r = br % MEMN;
        float ma = TA[r * EMBED + t];
        float mc = TC[r * EMBED + t];
        const int* toks = story + br * SS;
        #pragma unroll 4
        for (int s = 0; s < SS; ++s) {
            int tok = toks[s];
            float w = posw(s, SS, t);
            ma += Aw[tok * EMBED + t] * w;
            mc += Cw[tok * EMBED + t] * w;
        }
        memb[br * EMBED + t] = ma;
        outb[br * EMBED + t] = mc;
    }
}

// ---- Kernel 2 v6: R14's 4-wave hops body, standalone (un-poisoned measurement).
// 160 blocks x 256 thr. Split-K-4 logits; response/H split across halves;
// Hw rows read directly from global (L2/L3-hot), no HwT.
__global__ __launch_bounds__(256) void k_hops(const float* __restrict__ memb,
                                              const float* __restrict__ outb,
                                              const float* __restrict__ Hw,
                                              const float* __restrict__ Hb,
                                              const float* __restrict__ state,
                                              __hip_bfloat16* __restrict__ stateb) {
    __shared__ float lmem[MEMN][EMBED + 1];
    __shared__ float lout[MEMN][EMBED + 1];
    __shared__ float lstate[EMBED];
    __shared__ float lpart[4][52];
    __shared__ float lprobs[52];
    __shared__ float lrespp[2][EMBED];
    __shared__ float lHp[2][EMBED];

    int bn = blockIdx.x;
    int b  = bn / NQ;
    int t  = threadIdx.x;   // 256
    int w  = t >> 6;        // wave 0..3
    int l  = t & 63;
    int d  = t & 127;
    int h  = t >> 7;        // half 0/1

    {
        const float4* mb4 = (const float4*)(memb + (size_t)b * MEMN * EMBED);
        const float4* ob4 = (const float4*)(outb + (size_t)b * MEMN * EMBED);
        for (int i = t; i < MEMN * EMBED / 4; i += 256) {
            int r = i >> 5, c = (i & 31) << 2;
            float4 v = mb4[i];
            lmem[r][c] = v.x; lmem[r][c+1] = v.y; lmem[r][c+2] = v.z; lmem[r][c+3] = v.w;
            float4 u = ob4[i];
            lout[r][c] = u.x; lout[r][c+1] = u.y; lout[r][c+2] = u.z; lout[r][c+3] = u.w;
        }
        if (t < EMBED) lstate[t] = state[bn * EMBED + t];
    }
    float hbd = (t < EMBED) ? Hb[t] : 0.f;
    __syncthreads();

    for (int hop = 0; hop < NHOPS; ++hop) {
        // logits split-K-4: wave w covers dims [w*32, w*32+32), lane l = row
        if (l < MEMN) {
            int d0 = w << 5;
            float a0 = 0.f, a1 = 0.f, a2 = 0.f, a3 = 0.f;
            #pragma unroll
            for (int j = 0; j < 32; j += 4) {
                a0 += lmem[l][d0 + j]     * lstate[d0 + j];
                a1 += lmem[l][d0 + j + 1] * lstate[d0 + j + 1];
                a2 += lmem[l][d0 + j + 2] * lstate[d0 + j + 2];
                a3 += lmem[l][d0 + j + 3] * lstate[d0 + j + 3];
            }
            lpart[w][l] = (a0 + a1) + (a2 + a3);
        }
        __syncthreads();
        // softmax in wave 0
        if (t < 64) {
            float lg = (t < MEMN)
                ? (lpart[0][t] + lpart[1][t]) + (lpart[2][t] + lpart[3][t]) : -1e30f;
            float mx = lg;
            #pragma unroll
            for (int off = 32; off; off >>= 1) mx = fmaxf(mx, __shfl_xor(mx, off, 64));
            float e = (t < MEMN) ? __expf(lg - mx) : 0.f;
            float ss = e;
            #pragma unroll
            for (int off = 32; off; off >>= 1) ss += __shfl_xor(ss, off, 64);
            if (t < MEMN) lprobs[t] = e / ss;
        }
        __syncthreads();
        // response halves: half h covers rows [h*25, h*25+25)
        {
            float r0 = 0.f, r1 = 0.f;
            int k0 = h * 25;
            #pragma unroll
            for (int k = 0; k < 24; k += 2) {
                r0 += lprobs[k0 + k]     * lout[k0 + k][d];
                r1 += lprobs[k0 + k + 1] * lout[k0 + k + 1][d];
            }
            r0 += lprobs[k0 + 24] * lout[k0 + 24][d];
            lrespp[h][d] = r0 + r1;
        }
        __syncthreads();
        // H halves: half h covers k in [h*64, h*64+64); Hw row d contiguous
        {
            int ks = h << 6;
            const float4* hw4 = (const float4*)&Hw[(size_t)d * EMBED + ks];
            float a0 = 0.f, a1 = 0.f, a2 = 0.f, a3 = 0.f;
            #pragma unroll
            for (int j = 0; j < 16; ++j) {
                float4 wv = hw4[j];
                int k = ks + (j << 2);
                a0 += (lrespp[0][k]     + lrespp[1][k])     * wv.x;
                a1 += (lrespp[0][k + 1] + lrespp[1][k + 1]) * wv.y;
                a2 += (lrespp[0][k + 2] + lrespp[1][k + 2]) * wv.z;
                a3 += (lrespp[0][k + 3] + lrespp[1][k + 3]) * wv.w;
            }
            lHp[h][d] = (a0 + a1) + (a2 + a3);
        }
        __syncthreads();
        if (t < EMBED) {
            float ns = hbd + lstate[t] + lHp[0][t] + lHp[1][t];
            lstate[t] = ns;
        }
        __syncthreads();
    }
    if (t < EMBED)
        stateb[bn * EMBED + t] = __float2bfloat16(lstate[t]);
}

// ---- Kernel 3 (R8-exact): MFMA GEMM out[160,32000] ----
__global__ __launch_bounds__(256) void k_out(const __hip_bfloat16* __restrict__ stateb,
                                             const float* __restrict__ outw,
                                             float* __restrict__ out) {
    __shared__ __align__(16) __hip_bfloat16 Alds[BN][EMBED + 8];
    __shared__ __align__(16) __hip_bfloat16 Blds[NV][EMBED + 8];
    int t = threadIdx.x;
    int vbase = blockIdx.x * NV;

    #pragma unroll
    for (int i = 0; i < 10; ++i) {
        int e = t + i * 256;
        int row = e >> 4, c8 = (e & 15) << 3;
        *(int4*)&Alds[row][c8] = *(const int4*)&stateb[row * EMBED + c8];
    }
    #pragma unroll
    for (int i = 0; i < 8; ++i) {
        int e = t + i * 256;
        int row = e >> 5, c4 = (e & 31) << 2;
        float4 w = *(const float4*)&outw[(size_t)(vbase + row) * EMBED + c4];
        short4 p;
        p.x = f2bf(w.x); p.y = f2bf(w.y); p.z = f2bf(w.z); p.w = f2bf(w.w);
        *(short4*)&Blds[row][c4] = p;
    }
    __syncthreads();

    int wv = t >> 6;
    int l = t & 63;
    int col16 = l & 15;
    int kg = l >> 4;

    v8s bfrag[4];
    #pragma unroll
    for (int k4 = 0; k4 < 4; ++k4)
        bfrag[k4] = *(v8s*)&Blds[(wv << 4) + col16][k4 * 32 + kg * 8];

    v4f acc[10];
    #pragma unroll
    for (int m = 0; m < 10; ++m) acc[m] = (v4f){0.f, 0.f, 0.f, 0.f};

    #pragma unroll
    for (int k4 = 0; k4 < 4; ++k4) {
        #pragma unroll
        for (int m = 0; m < 10; ++m) {
            v8s af = *(v8s*)&Alds[m * 16 + col16][k4 * 32 + kg * 8];
            acc[m] = MFMA16(af, bfrag[k4], acc[m], 0, 0, 0);
        }
    }

    int colg = vbase + (wv << 4) + col16;
    #pragma unroll
    for (int m = 0; m < 10; ++m) {
        #pragma unroll
        for (int i = 0; i < 4; ++i) {
            out[(size_t)(m * 16 + kg * 4 + i) * VOCAB + colg] = acc[m][i];
        }
    }
}

extern "C" void kernel_launch(void* const* d_in, const int* in_sizes, int n_in,
                              void* d_out, int out_size, void* d_ws, size_t ws_size,
                              hipStream_t stream) {
    const int*   ctx_query = (const int*)  d_in[0];
    const int*   story     = (const int*)  d_in[1];
    const float* A_w       = (const float*)d_in[2];
    const float* C_w       = (const float*)d_in[3];
    const float* B_w       = (const float*)d_in[4];
    const float* H_w       = (const float*)d_in[5];
    const float* H_b       = (const float*)d_in[6];
    const float* out_w     = (const float*)d_in[7];
    const float* TA        = (const float*)d_in[8];
    const float* TC        = (const float*)d_in[9];
    float* out = (float*)d_out;

    float* ws    = (float*)d_ws;
    float* state = ws;                                   // 160*128 f32
    float* memb  = state + BN * EMBED;                   // 800*128 f32
    float* outb  = memb + BATCH * MEMN * EMBED;          // 800*128 f32
    __hip_bfloat16* stateb = (__hip_bfloat16*)(outb + BATCH * MEMN * EMBED); // 160*128 bf16

    k_embed<<<BN + BATCH * MEMN, 128, 0, stream>>>(
        ctx_query, story, B_w, A_w, C_w, TA, TC, state, memb, outb);
    k_hops<<<BN, 256, 0, stream>>>(memb, outb, H_w, H_b, state, stateb);
    k_out<<<VOCAB / NV, 256, 0, stream>>>(stateb, out_w, out);
}

// Round 16
// 29.780 us; speedup vs baseline: 4.1832x; 1.0379x over previous
//
#include <hip/hip_runtime.h>
#include <hip/hip_bf16.h>
#include <math.h>

#define EMBED 128
#define VOCAB 32000
#define MEMN  50
#define BATCH 16
#define NQ    10
#define SQ    20
#define SS    40
#define BN    (BATCH*NQ)   // 160
#define NHOPS 3
#define NV    64           // vocab rows per k_out block

typedef short v8s __attribute__((ext_vector_type(8)));
typedef float v4f __attribute__((ext_vector_type(4)));

#define MFMA16 __builtin_amdgcn_mfma_f32_16x16x32_bf16

__device__ __forceinline__ float posw(int j, int J, int k) {
    float jf = (float)(j + 1) / (float)J;
    return 1.0f - jf - ((float)(k + 1) / (float)EMBED) * (1.0f - 2.0f * jf);
}

__device__ __forceinline__ short f2bf(float f) {
    __hip_bfloat16 h = __float2bfloat16(f);
    return *(short*)&h;
}

// ---- Kernel 1 (R15-exact): query | story ----
__global__ void k_embed(const int* __restrict__ cq, const int* __restrict__ story,
                        const float* __restrict__ Bw, const float* __restrict__ Aw,
                        const float* __restrict__ Cw, const float* __restrict__ TA,
                        const float* __restrict__ TC,
                        float* __restrict__ state, float* __restrict__ memb,
                        float* __restrict__ outb) {
    int blk = blockIdx.x;
    int t = threadIdx.x;   // 128
    if (blk < BN) {
        float acc = 0.f;
        #pragma unroll
        for (int s = 0; s < SQ; ++s) {
            int tok = cq[blk * SQ + s];
            acc += Bw[tok * EMBED + t] * posw(s, SQ, t);
        }
        state[blk * EMBED + t] = acc;
    } else {
        int br = blk - BN;
        int r = br % MEMN;
        float ma = TA[r * EMBED + t];
        float mc = TC[r * EMBED + t];
        const int* toks = story + br * SS;
        #pragma unroll 4
        for (int s = 0; s < SS; ++s) {
            int tok = toks[s];
            float w = posw(s, SS, t);
            ma += Aw[tok * EMBED + t] * w;
            mc += Cw[tok * EMBED + t] * w;
        }
        memb[br * EMBED + t] = ma;
        outb[br * EMBED + t] = mc;
    }
}

// ---- Kernel 2 v7: v6 dataflow at 512 threads (8 waves).
// 2 blocks/CU (54KB LDS) -> 16 waves/CU TLP; logits split-K-8; resp/H 4-way.
__global__ __launch_bounds__(512) void k_hops(const float* __restrict__ memb,
                                              const float* __restrict__ outb,
                                              const float* __restrict__ Hw,
                                              const float* __restrict__ Hb,
                                              const float* __restrict__ state,
                                              __hip_bfloat16* __restrict__ stateb) {
    __shared__ float lmem[MEMN][EMBED + 1];
    __shared__ float lout[MEMN][EMBED + 1];
    __shared__ float lstate[EMBED];
    __shared__ float lpart[8][52];
    __shared__ float lprobs[52];
    __shared__ float lrespp[4][EMBED];
    __shared__ float lHp[4][EMBED];

    int bn = blockIdx.x;
    int b  = bn / NQ;
    int t  = threadIdx.x;   // 512
    int w  = t >> 6;        // wave 0..7
    int l  = t & 63;
    int d  = t & 127;
    int g  = t >> 7;        // quarter 0..3

    {
        const float4* mb4 = (const float4*)(memb + (size_t)b * MEMN * EMBED);
        const float4* ob4 = (const float4*)(outb + (size_t)b * MEMN * EMBED);
        for (int i = t; i < MEMN * EMBED / 4; i += 512) {
            int r = i >> 5, c = (i & 31) << 2;
            float4 v = mb4[i];
            lmem[r][c] = v.x; lmem[r][c+1] = v.y; lmem[r][c+2] = v.z; lmem[r][c+3] = v.w;
            float4 u = ob4[i];
            lout[r][c] = u.x; lout[r][c+1] = u.y; lout[r][c+2] = u.z; lout[r][c+3] = u.w;
        }
        if (t < EMBED) lstate[t] = state[bn * EMBED + t];
    }
    float hbd = (t < EMBED) ? Hb[t] : 0.f;
    __syncthreads();

    for (int hop = 0; hop < NHOPS; ++hop) {
        // logits split-K-8: wave w covers dims [w*16, w*16+16), lane l = row
        if (l < MEMN) {
            int d0 = w << 4;
            float a0 = 0.f, a1 = 0.f, a2 = 0.f, a3 = 0.f;
            #pragma unroll
            for (int j = 0; j < 16; j += 4) {
                a0 += lmem[l][d0 + j]     * lstate[d0 + j];
                a1 += lmem[l][d0 + j + 1] * lstate[d0 + j + 1];
                a2 += lmem[l][d0 + j + 2] * lstate[d0 + j + 2];
                a3 += lmem[l][d0 + j + 3] * lstate[d0 + j + 3];
            }
            lpart[w][l] = (a0 + a1) + (a2 + a3);
        }
        __syncthreads();
        // softmax in wave 0 (8 partials per row, conflict-free column reads)
        if (t < 64) {
            float lg = -1e30f;
            if (t < MEMN) {
                float s0 = (lpart[0][t] + lpart[1][t]) + (lpart[2][t] + lpart[3][t]);
                float s1 = (lpart[4][t] + lpart[5][t]) + (lpart[6][t] + lpart[7][t]);
                lg = s0 + s1;
            }
            float mx = lg;
            #pragma unroll
            for (int off = 32; off; off >>= 1) mx = fmaxf(mx, __shfl_xor(mx, off, 64));
            float e = (t < MEMN) ? __expf(lg - mx) : 0.f;
            float ss = e;
            #pragma unroll
            for (int off = 32; off; off >>= 1) ss += __shfl_xor(ss, off, 64);
            if (t < MEMN) lprobs[t] = e / ss;
        }
        __syncthreads();
        // response 4-way: quarter g covers rows {g, g+4, ...} (13/13/12/12)
        {
            float r0 = 0.f, r1 = 0.f;
            #pragma unroll
            for (int k = 0; k + 4 < MEMN; k += 8) {
                int ra = g + k, rb = g + k + 4;
                r0 += lprobs[ra] * lout[ra][d];
                r1 += lprobs[rb] * lout[rb][d];
            }
            if (g < 2) { int ra = g + 48; r0 += lprobs[ra] * lout[ra][d]; }
            lrespp[g][d] = r0 + r1;
        }
        __syncthreads();
        // H 4-way: quarter g covers k in [g*32, g*32+32); lrespp reads broadcast
        {
            int ks = g << 5;
            const float4* hw4 = (const float4*)&Hw[(size_t)d * EMBED + ks];
            float a0 = 0.f, a1 = 0.f, a2 = 0.f, a3 = 0.f;
            #pragma unroll
            for (int j = 0; j < 8; ++j) {
                float4 wv = hw4[j];
                int k = ks + (j << 2);
                float v0 = (lrespp[0][k]     + lrespp[1][k])     + (lrespp[2][k]     + lrespp[3][k]);
                float v1 = (lrespp[0][k + 1] + lrespp[1][k + 1]) + (lrespp[2][k + 1] + lrespp[3][k + 1]);
                float v2 = (lrespp[0][k + 2] + lrespp[1][k + 2]) + (lrespp[2][k + 2] + lrespp[3][k + 2]);
                float v3 = (lrespp[0][k + 3] + lrespp[1][k + 3]) + (lrespp[2][k + 3] + lrespp[3][k + 3]);
                a0 += v0 * wv.x; a1 += v1 * wv.y; a2 += v2 * wv.z; a3 += v3 * wv.w;
            }
            lHp[g][d] = (a0 + a1) + (a2 + a3);
        }
        __syncthreads();
        if (t < EMBED) {
            float ns = hbd + lstate[t]
                     + (lHp[0][t] + lHp[1][t]) + (lHp[2][t] + lHp[3][t]);
            lstate[t] = ns;
        }
        __syncthreads();
    }
    if (t < EMBED)
        stateb[bn * EMBED + t] = __float2bfloat16(lstate[t]);
}

// ---- Kernel 3 (R15-exact): MFMA GEMM out[160,32000] ----
__global__ __launch_bounds__(256) void k_out(const __hip_bfloat16* __restrict__ stateb,
                                             const float* __restrict__ outw,
                                             float* __restrict__ out) {
    __shared__ __align__(16) __hip_bfloat16 Alds[BN][EMBED + 8];
    __shared__ __align__(16) __hip_bfloat16 Blds[NV][EMBED + 8];
    int t = threadIdx.x;
    int vbase = blockIdx.x * NV;

    #pragma unroll
    for (int i = 0; i < 10; ++i) {
        int e = t + i * 256;
        int row = e >> 4, c8 = (e & 15) << 3;
        *(int4*)&Alds[row][c8] = *(const int4*)&stateb[row * EMBED + c8];
    }
    #pragma unroll
    for (int i = 0; i < 8; ++i) {
        int e = t + i * 256;
        int row = e >> 5, c4 = (e & 31) << 2;
        float4 w = *(const float4*)&outw[(size_t)(vbase + row) * EMBED + c4];
        short4 p;
        p.x = f2bf(w.x); p.y = f2bf(w.y); p.z = f2bf(w.z); p.w = f2bf(w.w);
        *(short4*)&Blds[row][c4] = p;
    }
    __syncthreads();

    int wv = t >> 6;
    int l = t & 63;
    int col16 = l & 15;
    int kg = l >> 4;

    v8s bfrag[4];
    #pragma unroll
    for (int k4 = 0; k4 < 4; ++k4)
        bfrag[k4] = *(v8s*)&Blds[(wv << 4) + col16][k4 * 32 + kg * 8];

    v4f acc[10];
    #pragma unroll
    for (int m = 0; m < 10; ++m) acc[m] = (v4f){0.f, 0.f, 0.f, 0.f};

    #pragma unroll
    for (int k4 = 0; k4 < 4; ++k4) {
        #pragma unroll
        for (int m = 0; m < 10; ++m) {
            v8s af = *(v8s*)&Alds[m * 16 + col16][k4 * 32 + kg * 8];
            acc[m] = MFMA16(af, bfrag[k4], acc[m], 0, 0, 0);
        }
    }

    int colg = vbase + (wv << 4) + col16;
    #pragma unroll
    for (int m = 0; m < 10; ++m) {
        #pragma unroll
        for (int i = 0; i < 4; ++i) {
            out[(size_t)(m * 16 + kg * 4 + i) * VOCAB + colg] = acc[m][i];
        }
    }
}

extern "C" void kernel_launch(void* const* d_in, const int* in_sizes, int n_in,
                              void* d_out, int out_size, void* d_ws, size_t ws_size,
                              hipStream_t stream) {
    const int*   ctx_query = (const int*)  d_in[0];
    const int*   story     = (const int*)  d_in[1];
    const float* A_w       = (const float*)d_in[2];
    const float* C_w       = (const float*)d_in[3];
    const float* B_w       = (const float*)d_in[4];
    const float* H_w       = (const float*)d_in[5];
    const float* H_b       = (const float*)d_in[6];
    const float* out_w     = (const float*)d_in[7];
    const float* TA        = (const float*)d_in[8];
    const float* TC        = (const float*)d_in[9];
    float* out = (float*)d_out;

    float* ws    = (float*)d_ws;
    float* state = ws;                                   // 160*128 f32
    float* memb  = state + BN * EMBED;                   // 800*128 f32
    float* outb  = memb + BATCH * MEMN * EMBED;          // 800*128 f32
    __hip_bfloat16* stateb = (__hip_bfloat16*)(outb + BATCH * MEMN * EMBED); // 160*128 bf16

    k_embed<<<BN + BATCH * MEMN, 128, 0, stream>>>(
        ctx_query, story, B_w, A_w, C_w, TA, TC, state, memb, outb);
    k_hops<<<BN, 512, 0, stream>>>(memb, outb, H_w, H_b, state, stateb);
    k_out<<<VOCAB / NV, 256, 0, stream>>>(stateb, out_w, out);
}